// Round 1
// baseline (10.093 us; speedup 1.0000x reference)
//
#include <hip/hip_runtime.h>

#define N_CTRL 64
#define NSEG 67.0f   // N_KNOTS - 1 = 67 spans over [0,1]

// Evaluate cubic B-spline y[n] = sum_i B_{i,3}(x[n]) * c[i] on uniform knots.
// Only 4 basis functions are nonzero per x; uniform knots => closed-form
// canonical cubic B-spline weights. Indices clipped to [0,64) exactly as the
// reference's truncated basis table does at the boundaries.
__global__ __launch_bounds__(256) void spline_eval_kernel(
    const float* __restrict__ x,
    const float* __restrict__ ctrl,
    float* __restrict__ out,
    int n4, int n)
{
    __shared__ float c[N_CTRL];
    if (threadIdx.x < N_CTRL) c[threadIdx.x] = ctrl[threadIdx.x];
    __syncthreads();

    const float4* __restrict__ x4 = (const float4*)x;
    float4* __restrict__ o4 = (float4*)out;

    int idx = blockIdx.x * blockDim.x + threadIdx.x;
    int stride = gridDim.x * blockDim.x;

    for (int i = idx; i < n4; i += stride) {
        float4 xv = x4[i];
        float xs[4] = {xv.x, xv.y, xv.z, xv.w};
        float ys[4];
        #pragma unroll
        for (int k = 0; k < 4; ++k) {
            float u = xs[k] * NSEG;
            int j = (int)u;
            j = j > 66 ? 66 : j;          // x in [0,1); guard float edge at 1.0
            j = j < 0 ? 0 : j;
            float s = u - (float)j;
            float s2 = s * s;
            float s3 = s2 * s;
            float om = 1.0f - s;
            const float c6 = 1.0f / 6.0f;
            float b0 = om * om * om * c6;                       // i = j-3
            float b1 = (3.0f*s3 - 6.0f*s2 + 4.0f) * c6;         // i = j-2
            float b2 = (-3.0f*s3 + 3.0f*s2 + 3.0f*s + 1.0f)*c6; // i = j-1
            float b3 = s3 * c6;                                 // i = j
            float acc = 0.0f;
            int i0 = j - 3;
            if (i0     >= 0 && i0     < N_CTRL) acc += b0 * c[i0];
            if (i0 + 1 >= 0 && i0 + 1 < N_CTRL) acc += b1 * c[i0 + 1];
            if (i0 + 2 >= 0 && i0 + 2 < N_CTRL) acc += b2 * c[i0 + 2];
            if (j      >= 0 && j      < N_CTRL) acc += b3 * c[j];
            ys[k] = acc;
        }
        float4 yv;
        yv.x = ys[0]; yv.y = ys[1]; yv.z = ys[2]; yv.w = ys[3];
        o4[i] = yv;
    }

    // Scalar tail (n not divisible by 4) — handled by the first few threads.
    int tail_start = n4 * 4;
    int t = tail_start + idx;
    if (t < n) {
        float u = x[t] * NSEG;
        int j = (int)u;
        j = j > 66 ? 66 : j;
        j = j < 0 ? 0 : j;
        float s = u - (float)j;
        float s2 = s * s, s3 = s2 * s;
        float om = 1.0f - s;
        const float c6 = 1.0f / 6.0f;
        float b0 = om * om * om * c6;
        float b1 = (3.0f*s3 - 6.0f*s2 + 4.0f) * c6;
        float b2 = (-3.0f*s3 + 3.0f*s2 + 3.0f*s + 1.0f) * c6;
        float b3 = s3 * c6;
        float acc = 0.0f;
        int i0 = j - 3;
        if (i0     >= 0 && i0     < N_CTRL) acc += b0 * c[i0];
        if (i0 + 1 >= 0 && i0 + 1 < N_CTRL) acc += b1 * c[i0 + 1];
        if (i0 + 2 >= 0 && i0 + 2 < N_CTRL) acc += b2 * c[i0 + 2];
        if (j      >= 0 && j      < N_CTRL) acc += b3 * c[j];
        out[t] = acc;
    }
}

extern "C" void kernel_launch(void* const* d_in, const int* in_sizes, int n_in,
                              void* d_out, int out_size, void* d_ws, size_t ws_size,
                              hipStream_t stream) {
    const float* x    = (const float*)d_in[0];
    // d_in[1] = knots (uniform linspace(0,1,68)) — closed-form, not needed.
    const float* ctrl = (const float*)d_in[2];
    float* out = (float*)d_out;

    int n  = in_sizes[0];       // 1,000,000
    int n4 = n / 4;             // float4 chunks

    int block = 256;
    int grid = (n4 + block - 1) / block;  // ~977 blocks for 1M points
    if (grid < 1) grid = 1;

    spline_eval_kernel<<<grid, block, 0, stream>>>(x, ctrl, out, n4, n);
}